// Round 5
// baseline (1966.428 us; speedup 1.0000x reference)
//
#include <hip/hip_runtime.h>

#define BB 4
#define NN 4096
#define CC 128
#define DD 131          // 3 + 128
#define NPOINT 1024
#define NW 8            // workers (blocks) per batch

typedef float f32x4 __attribute__((ext_vector_type(4)));

// IEEE-exact, non-fusable fp32 ops (intrinsics are immune to -ffp-contract)
__device__ __forceinline__ float fmul_(float a, float b) { return __fmul_rn(a, b); }
__device__ __forceinline__ float fadd_(float a, float b) { return __fadd_rn(a, b); }

// ---------------------------------------------------------------------------
// dist[b][i][j] = fl(fl(aa_i + aa_j) - 2*ab_ij)   (x2 exact, one rounding)
//   ab = ascending-k single-accumulator FMA chain (Eigen gebp order)
//   aa = XLA:CPU VF8-IC4 reduce. VERIFIED bit-exact (rounds 11-18, absmax 0).
// 64x64 tile, 4x4/thread, k-major LDS, two K chunks. Arithmetic order FROZEN.
// ---------------------------------------------------------------------------
__global__ __launch_bounds__(256) void dist_kernel(const float* __restrict__ points,
                                                   const float* __restrict__ features,
                                                   float* __restrict__ dist) {
    __shared__ float As[67][64];
    __shared__ float Bs[67][64];
    __shared__ float s_aai[64];
    __shared__ float s_aaj[64];

    const int b  = blockIdx.z;
    const int i0 = blockIdx.x * 64;
    const int j0 = blockIdx.y * 64;
    const int tid = threadIdx.x;
    const int r = tid & 63, g = tid >> 6;
    const int tx = tid & 15;
    const int ty = tid >> 4;

    for (int k = g; k < 64; k += 4) {
        float av, bv;
        if (k < 3) {
            av = points[((size_t)b * NN + i0 + r) * 3 + k];
            bv = points[((size_t)b * NN + j0 + r) * 3 + k];
        } else {
            const float* frow = features + ((size_t)b * CC + (k - 3)) * NN;
            av = frow[i0 + r];
            bv = frow[j0 + r];
        }
        As[k][r] = av;
        Bs[k][r] = bv;
    }
    __syncthreads();

    float ph[4][8];
    if (tid < 128) {
        const int rr = tid & 63;
        const float (*S)[64] = (tid < 64) ? As : Bs;
#pragma unroll
        for (int j = 0; j < 4; ++j)
#pragma unroll
            for (int l = 0; l < 8; ++l) {
                float x = S[8 * j + l][rr];
                ph[j][l] = fmul_(x, x);                       // it = 0
            }
#pragma unroll
        for (int j = 0; j < 4; ++j)
#pragma unroll
            for (int l = 0; l < 8; ++l) {
                float x = S[32 + 8 * j + l][rr];
                ph[j][l] = fadd_(ph[j][l], fmul_(x, x));      // it = 1
            }
    }

    float acc[4][4];
#pragma unroll
    for (int p = 0; p < 4; ++p)
#pragma unroll
        for (int q = 0; q < 4; ++q) acc[p][q] = 0.f;

#pragma unroll 4
    for (int kk = 0; kk < 64; ++kk) {
        float4 a4 = *(const float4*)&As[kk][4 * ty];
        float4 b4 = *(const float4*)&Bs[kk][4 * tx];
        const float a[4] = {a4.x, a4.y, a4.z, a4.w};
        const float c[4] = {b4.x, b4.y, b4.z, b4.w};
#pragma unroll
        for (int p = 0; p < 4; ++p)
#pragma unroll
            for (int q = 0; q < 4; ++q)
                acc[p][q] = __builtin_fmaf(a[p], c[q], acc[p][q]);
    }
    __syncthreads();

    for (int k = g; k < 67; k += 4) {
        const float* frow = features + ((size_t)b * CC + (64 + k - 3)) * NN;
        As[k][r] = frow[i0 + r];
        Bs[k][r] = frow[j0 + r];
    }
    __syncthreads();

    if (tid < 128) {
        const int rr = tid & 63;
        const float (*S)[64] = (tid < 64) ? As : Bs;
#pragma unroll
        for (int j = 0; j < 4; ++j)
#pragma unroll
            for (int l = 0; l < 8; ++l) {
                float x = S[8 * j + l][rr];
                ph[j][l] = fadd_(ph[j][l], fmul_(x, x));      // it = 2
            }
#pragma unroll
        for (int j = 0; j < 4; ++j)
#pragma unroll
            for (int l = 0; l < 8; ++l) {
                float x = S[32 + 8 * j + l][rr];
                ph[j][l] = fadd_(ph[j][l], fmul_(x, x));      // it = 3
            }
        float v[8];
#pragma unroll
        for (int l = 0; l < 8; ++l)
            v[l] = fadd_(fadd_(fadd_(ph[0][l], ph[1][l]), ph[2][l]), ph[3][l]);
        float h4_0 = fadd_(v[0], v[4]), h4_1 = fadd_(v[1], v[5]);
        float h4_2 = fadd_(v[2], v[6]), h4_3 = fadd_(v[3], v[7]);
        float h1 = fadd_(fadd_(h4_0, h4_2), fadd_(h4_1, h4_3));
        float t0 = S[64][rr], t1 = S[65][rr], t2 = S[66][rr];
        h1 = fadd_(h1, fmul_(t0, t0));
        h1 = fadd_(h1, fmul_(t1, t1));
        h1 = fadd_(h1, fmul_(t2, t2));
        if (tid < 64) s_aai[rr] = h1; else s_aaj[rr] = h1;
    }

#pragma unroll 4
    for (int kk = 0; kk < 67; ++kk) {
        float4 a4 = *(const float4*)&As[kk][4 * ty];
        float4 b4 = *(const float4*)&Bs[kk][4 * tx];
        const float a[4] = {a4.x, a4.y, a4.z, a4.w};
        const float c[4] = {b4.x, b4.y, b4.z, b4.w};
#pragma unroll
        for (int p = 0; p < 4; ++p)
#pragma unroll
            for (int q = 0; q < 4; ++q)
                acc[p][q] = __builtin_fmaf(a[p], c[q], acc[p][q]);
    }
    __syncthreads();

#pragma unroll
    for (int p = 0; p < 4; ++p) {
        const int i = i0 + 4 * ty + p;
        const float aai = s_aai[4 * ty + p];
        float4 o;
        o.x = __builtin_fmaf(-2.0f, acc[p][0], fadd_(aai, s_aaj[4 * tx + 0]));
        o.y = __builtin_fmaf(-2.0f, acc[p][1], fadd_(aai, s_aaj[4 * tx + 1]));
        o.z = __builtin_fmaf(-2.0f, acc[p][2], fadd_(aai, s_aaj[4 * tx + 2]));
        o.w = __builtin_fmaf(-2.0f, acc[p][3], fadd_(aai, s_aaj[4 * tx + 3]));
        *(float4*)&dist[((size_t)b * NN + i) * NN + j0 + 4 * tx] = o;
    }
}

// ---------------------------------------------------------------------------
// DPP wave64 argmax combine with first-occurrence index tiebreak.
// ---------------------------------------------------------------------------
template <int CTRL>
__device__ __forceinline__ void dpp_step(float& v, int& i) {
    int ovb = __builtin_amdgcn_update_dpp(0, __float_as_int(v), CTRL, 0xF, 0xF, false);
    int oi  = __builtin_amdgcn_update_dpp(0, i,                 CTRL, 0xF, 0xF, false);
    float ov = __int_as_float(ovb);
    if (ov > v || (ov == v && oi < i)) { v = ov; i = oi; }
}

// local (value, index) update, ascending-index visitation => first-occurrence
__device__ __forceinline__ void upd(float& bv, int& bi, float m, int idx) {
    if (m > bv) { bv = m; bi = idx; }
}

// ---------------------------------------------------------------------------
// Cross-worker exchange state. Device globals are zero-initialized at module
// load; the done-handshake below re-zeroes them at the end of every launch so
// repeated dispatches (timing loop, rocprof replay) start clean.
// Slots are parity-double-buffered: a worker cannot overwrite its parity-p
// slot for step k+2 before passing the parity-(1-p) spin of step k+1, which
// requires every worker to have passed the parity-p spin of step k. => no
// reader can ever miss its wanted (tag,key). Lap-free by construction.
// ---------------------------------------------------------------------------
__device__ unsigned long long g_slots[BB][2][NW];   // [batch][parity][worker]
__device__ unsigned int g_done[BB];

// ---------------------------------------------------------------------------
// Sequential FPS — R23: 8 single-wave workgroups per batch (32 blocks total).
// R12-R22 post-mortem: every single-CU variant lands at 2800-3400 cyc/step =>
// per-CU line-fill MLP cap on the 16 KB row gather is the floor (R17's 8-wave
// null proves cap is per-CU, not per-wave). Fix: spread the row over 8 CUs.
// Worker w owns cols [512w, 512w+512): ingest 2 KB (32 lines, one latency
// quantum, 8x aggregate MLP), 8 mind cols/lane, wave DPP argmax, then an
// agent-scope slot exchange: write packed key [tag:20|val:32|idxinv:12] to
// g_slots[b][k&1][w], spin until all 8 tags==k+1 (one 64B line), u64-max
// butterfly over lanes 0-7 -> uniform last. First-occurrence exact: ascending
// in-lane scan, idx-tiebreak DPP, idx-inverted key (max => smallest idx),
// disjoint per-worker index ranges. Step model: ingest ~900 + scan/DPP ~250 +
// exchange ~600-1200 => ~1700-2400 cyc vs 2832 single-CU floor.
// ---------------------------------------------------------------------------
__global__ __launch_bounds__(64, 1) void fps_kernel(const float* __restrict__ dist,
                                                    int* __restrict__ out) {
    const int bid = blockIdx.x;
    const int b = bid >> 3;          // batch
    const int w = bid & 7;           // worker within batch
    const int lane = threadIdx.x;    // single wave
    const float* Dm = dist + (size_t)b * NN * NN;

    __shared__ int s_hist[NPOINT];   // used by worker 0 only

    f32x4 mA = (f32x4)(1e10f), mB = (f32x4)(1e10f);
    int last = 0;

    const unsigned vb = 2048u * w + 16u * lane;   // byte offset of quad A
    const int baseA = 512 * w + 4 * lane;
    const int baseB = baseA + 256;

    for (int k = 0; k < NPOINT; ++k) {
        if (w == 0 && lane == 0) s_hist[k] = last;
        if (k == NPOINT - 1) break;   // last output needs no further work

        const float* rowbase = Dm + (size_t)last * NN;   // uniform, SALU
        f32x4 dA, dB;
        asm volatile("global_load_dwordx4 %0, %1, %2"             : "=v"(dA) : "v"(vb), "s"(rowbase));
        asm volatile("global_load_dwordx4 %0, %1, %2 offset:1024" : "=v"(dB) : "v"(vb), "s"(rowbase));
        asm volatile("s_waitcnt vmcnt(0)" ::: "memory");
        __builtin_amdgcn_sched_barrier(0);   // nothing crosses the wait

        mA[0] = fminf(mA[0], dA[0]); mA[1] = fminf(mA[1], dA[1]);
        mA[2] = fminf(mA[2], dA[2]); mA[3] = fminf(mA[3], dA[3]);
        mB[0] = fminf(mB[0], dB[0]); mB[1] = fminf(mB[1], dB[1]);
        mB[2] = fminf(mB[2], dB[2]); mB[3] = fminf(mB[3], dB[3]);

        // ascending-index scan => first occurrence within the lane
        float bv = mA[0]; int bi = baseA;
        upd(bv, bi, mA[1], baseA + 1); upd(bv, bi, mA[2], baseA + 2);
        upd(bv, bi, mA[3], baseA + 3);
        upd(bv, bi, mB[0], baseB);     upd(bv, bi, mB[1], baseB + 1);
        upd(bv, bi, mB[2], baseB + 2); upd(bv, bi, mB[3], baseB + 3);

        // wave64 DPP argmax -> lane 63, readlane => wave-uniform
        dpp_step<0xB1>(bv, bi);    // quad_perm [1,0,3,2]  (xor 1)
        dpp_step<0x4E>(bv, bi);    // quad_perm [2,3,0,1]  (xor 2)
        dpp_step<0x141>(bv, bi);   // row_half_mirror      (xor 4)
        dpp_step<0x140>(bv, bi);   // row_mirror           (xor 8)
        dpp_step<0x142>(bv, bi);   // row_bcast15
        dpp_step<0x143>(bv, bi);   // row_bcast31
        float wv = __int_as_float(__builtin_amdgcn_readlane(__float_as_int(bv), 63));
        int   wi = __builtin_amdgcn_readlane(bi, 63);

        // pack monotone key: [tag:20 | val:32 | 4095-idx:12]
        unsigned u = __float_as_uint(wv);
        u = ((int)u >= 0) ? (u | 0x80000000u) : ~u;
        if (wv == 0.0f) u = 0x80000000u;   // normalize -0/+0
        const unsigned long long want = (unsigned long long)(k + 1);
        const unsigned long long mykey =
            (want << 44) | ((unsigned long long)u << 12) | (unsigned)(4095 - wi);

        const int p = k & 1;
        if (lane == 0)
            __hip_atomic_store(&g_slots[b][p][w], mykey,
                               __ATOMIC_RELAXED, __HIP_MEMORY_SCOPE_AGENT);

        // spin: lanes 0-7 poll the 8 slots (one 64B line) until tag==k+1
        unsigned long long key = want << 44;   // lanes >= 8: vacuously ready
        for (;;) {
            unsigned long long v = want << 44;
            if (lane < NW)
                v = __hip_atomic_load(&g_slots[b][p][lane],
                                      __ATOMIC_RELAXED, __HIP_MEMORY_SCOPE_AGENT);
            if (__all((int)((v >> 44) == want))) { key = v; break; }
        }

        // u64 max butterfly over lanes 0-7 (quads + half-row mirror)
#define DPP64(CTRL)                                                                     \
        {                                                                               \
            int lo_ = __builtin_amdgcn_update_dpp(0, (int)(unsigned)key, CTRL, 0xF, 0xF, false); \
            int hi_ = __builtin_amdgcn_update_dpp(0, (int)(unsigned)(key >> 32), CTRL, 0xF, 0xF, false); \
            unsigned long long o_ = ((unsigned long long)(unsigned)hi_ << 32) | (unsigned)lo_;   \
            if (o_ > key) key = o_;                                                     \
        }
        DPP64(0xB1)    // xor 1
        DPP64(0x4E)    // xor 2
        DPP64(0x141)   // half-row mirror == xor 4 after quads uniform
#undef DPP64

        const int lo_s = __builtin_amdgcn_readlane((int)(unsigned)key, 0);
        last = 4095 - (lo_s & 0xFFF);   // SGPR-uniform
    }

    // flush history (worker 0): 16 ints per lane, coalesced
    if (w == 0) {
#pragma unroll
        for (int c = 0; c < 16; ++c)
            out[b * NPOINT + 64 * c + lane] = s_hist[64 * c + lane];
    }

    // self-clean handshake: 8th arriver zeroes slots+counter for next launch.
    // Safe: the 8th done-increment implies all workers passed the final spin.
    if (lane == 0) {
        unsigned old = __hip_atomic_fetch_add(&g_done[b], 1u,
                                              __ATOMIC_RELAXED, __HIP_MEMORY_SCOPE_AGENT);
        if (old == NW - 1) {
#pragma unroll
            for (int i = 0; i < NW; ++i) {
                __hip_atomic_store(&g_slots[b][0][i], 0ull,
                                   __ATOMIC_RELAXED, __HIP_MEMORY_SCOPE_AGENT);
                __hip_atomic_store(&g_slots[b][1][i], 0ull,
                                   __ATOMIC_RELAXED, __HIP_MEMORY_SCOPE_AGENT);
            }
            __hip_atomic_store(&g_done[b], 0u,
                               __ATOMIC_RELAXED, __HIP_MEMORY_SCOPE_AGENT);
        }
    }
}

// ---------------------------------------------------------------------------
extern "C" void kernel_launch(void* const* d_in, const int* in_sizes, int n_in,
                              void* d_out, int out_size, void* d_ws, size_t ws_size,
                              hipStream_t stream) {
    const float* points   = (const float*)d_in[0];
    const float* features = (const float*)d_in[1];
    int* out = (int*)d_out;

    float* dist = (float*)d_ws;   // exactly 256 MiB

    dim3 g(NN / 64, NN / 64, BB);
    dist_kernel<<<g, 256, 0, stream>>>(points, features, dist);

    fps_kernel<<<BB * NW, 64, 0, stream>>>(dist, out);
}

// Round 6
// 1526.225 us; speedup vs baseline: 1.2884x; 1.2884x over previous
//
#include <hip/hip_runtime.h>

#define BB 4
#define NN 4096
#define CC 128
#define DD 131          // 3 + 128
#define NPOINT 1024

// IEEE-exact, non-fusable fp32 ops (intrinsics are immune to -ffp-contract)
__device__ __forceinline__ float fmul_(float a, float b) { return __fmul_rn(a, b); }
__device__ __forceinline__ float fadd_(float a, float b) { return __fadd_rn(a, b); }

// ---------------------------------------------------------------------------
// dist[b][i][j] = fl(fl(aa_i + aa_j) - 2*ab_ij)   (x2 exact, one rounding)
//   ab = ascending-k single-accumulator FMA chain (Eigen gebp order)
//   aa = XLA:CPU VF8-IC4 reduce. Bit-exact semantics FROZEN per output.
// R24: 128x128 tile, 8x8/thread (was 64x64, 4x4). Rationale: R0-R23 counters
// put dist at ~300us; LDS-traffic model (2 B/FMA at 4x4) = ~330us at the
// 85 B/cyc/CU ds_read_b128 ceiling => LDS-BW-bound. 8x8 halves LDS bytes
// per FMA => FMA-issue-bound (~112us floor). Per-output arithmetic chain
// (ascending k, single acc, two chunks 0..63 / 64..130) and the aa tree are
// IDENTICAL to the verified kernel — only thread<->output mapping and LDS
// geometry changed. px = ((tx&3)<<2)|(tx>>2) spreads the 8-float B-fragment
// reads across bank quads (px%4 = tx>>2) => conflict-free; outputs follow px.
// ---------------------------------------------------------------------------
__global__ __launch_bounds__(256) void dist_kernel(const float* __restrict__ points,
                                                   const float* __restrict__ features,
                                                   float* __restrict__ dist) {
    __shared__ float As[67][128];
    __shared__ float Bs[67][128];
    __shared__ float s_aai[128];
    __shared__ float s_aaj[128];

    const int b  = blockIdx.z;
    const int i0 = blockIdx.x * 128;
    const int j0 = blockIdx.y * 128;
    const int tid = threadIdx.x;
    const int r = tid & 127, g = tid >> 7;       // staging: 2 groups x 128
    const int tx = tid & 15;
    const int tyy = tid >> 4;                    // 16x16 thread grid
    const int px = ((tx & 3) << 2) | (tx >> 2);  // bank-spread col-group perm

    // ---- stage chunk 1: k = 0..63
    for (int k = g; k < 64; k += 2) {
        float av, bv;
        if (k < 3) {
            av = points[((size_t)b * NN + i0 + r) * 3 + k];
            bv = points[((size_t)b * NN + j0 + r) * 3 + k];
        } else {
            const float* frow = features + ((size_t)b * CC + (k - 3)) * NN;
            av = frow[i0 + r];
            bv = frow[j0 + r];
        }
        As[k][r] = av;
        Bs[k][r] = bv;
    }
    __syncthreads();

    // ---- aa phases it=0,1 (k = 0..31, 32..63); 256 threads = 128 i + 128 j
    float ph[4][8];
    {
        const int rr = tid & 127;
        const float (*S)[128] = (tid < 128) ? As : Bs;
#pragma unroll
        for (int j = 0; j < 4; ++j)
#pragma unroll
            for (int l = 0; l < 8; ++l) {
                float x = S[8 * j + l][rr];
                ph[j][l] = fmul_(x, x);                       // it = 0
            }
#pragma unroll
        for (int j = 0; j < 4; ++j)
#pragma unroll
            for (int l = 0; l < 8; ++l) {
                float x = S[32 + 8 * j + l][rr];
                ph[j][l] = fadd_(ph[j][l], fmul_(x, x));      // it = 1
            }
    }

    float acc[8][8];
#pragma unroll
    for (int p = 0; p < 8; ++p)
#pragma unroll
        for (int q = 0; q < 8; ++q) acc[p][q] = 0.f;

    // ---- FMA chunk 1: k = 0..63 (ascending, single accumulator per output)
#pragma unroll 2
    for (int kk = 0; kk < 64; ++kk) {
        float4 a0 = *(const float4*)&As[kk][8 * tyy];
        float4 a1 = *(const float4*)&As[kk][8 * tyy + 4];
        float4 b0 = *(const float4*)&Bs[kk][8 * px];
        float4 b1 = *(const float4*)&Bs[kk][8 * px + 4];
        const float a[8] = {a0.x, a0.y, a0.z, a0.w, a1.x, a1.y, a1.z, a1.w};
        const float c[8] = {b0.x, b0.y, b0.z, b0.w, b1.x, b1.y, b1.z, b1.w};
#pragma unroll
        for (int p = 0; p < 8; ++p)
#pragma unroll
            for (int q = 0; q < 8; ++q)
                acc[p][q] = __builtin_fmaf(a[p], c[q], acc[p][q]);
    }
    __syncthreads();

    // ---- stage chunk 2: local k = 0..66  <->  global k = 64..130
    for (int k = g; k < 67; k += 2) {
        const float* frow = features + ((size_t)b * CC + (64 + k - 3)) * NN;
        As[k][r] = frow[i0 + r];
        Bs[k][r] = frow[j0 + r];
    }
    __syncthreads();

    // ---- aa phases it=2,3 + finalize (identical tree to verified kernel)
    {
        const int rr = tid & 127;
        const float (*S)[128] = (tid < 128) ? As : Bs;
#pragma unroll
        for (int j = 0; j < 4; ++j)
#pragma unroll
            for (int l = 0; l < 8; ++l) {
                float x = S[8 * j + l][rr];
                ph[j][l] = fadd_(ph[j][l], fmul_(x, x));      // it = 2
            }
#pragma unroll
        for (int j = 0; j < 4; ++j)
#pragma unroll
            for (int l = 0; l < 8; ++l) {
                float x = S[32 + 8 * j + l][rr];
                ph[j][l] = fadd_(ph[j][l], fmul_(x, x));      // it = 3
            }
        float v[8];
#pragma unroll
        for (int l = 0; l < 8; ++l)
            v[l] = fadd_(fadd_(fadd_(ph[0][l], ph[1][l]), ph[2][l]), ph[3][l]);
        float h4_0 = fadd_(v[0], v[4]), h4_1 = fadd_(v[1], v[5]);
        float h4_2 = fadd_(v[2], v[6]), h4_3 = fadd_(v[3], v[7]);
        float h1 = fadd_(fadd_(h4_0, h4_2), fadd_(h4_1, h4_3));
        float t0 = S[64][rr], t1 = S[65][rr], t2 = S[66][rr];
        h1 = fadd_(h1, fmul_(t0, t0));
        h1 = fadd_(h1, fmul_(t1, t1));
        h1 = fadd_(h1, fmul_(t2, t2));
        if (tid < 128) s_aai[rr] = h1; else s_aaj[rr] = h1;
    }

    // ---- FMA chunk 2: global k = 64..130
#pragma unroll 2
    for (int kk = 0; kk < 67; ++kk) {
        float4 a0 = *(const float4*)&As[kk][8 * tyy];
        float4 a1 = *(const float4*)&As[kk][8 * tyy + 4];
        float4 b0 = *(const float4*)&Bs[kk][8 * px];
        float4 b1 = *(const float4*)&Bs[kk][8 * px + 4];
        const float a[8] = {a0.x, a0.y, a0.z, a0.w, a1.x, a1.y, a1.z, a1.w};
        const float c[8] = {b0.x, b0.y, b0.z, b0.w, b1.x, b1.y, b1.z, b1.w};
#pragma unroll
        for (int p = 0; p < 8; ++p)
#pragma unroll
            for (int q = 0; q < 8; ++q)
                acc[p][q] = __builtin_fmaf(a[p], c[q], acc[p][q]);
    }
    __syncthreads();

    // ---- epilogue: x2-exact combine, one rounding; cols follow px
#pragma unroll
    for (int p = 0; p < 8; ++p) {
        const int i = i0 + 8 * tyy + p;
        const float aai = s_aai[8 * tyy + p];
        float4 o0, o1;
        o0.x = __builtin_fmaf(-2.0f, acc[p][0], fadd_(aai, s_aaj[8 * px + 0]));
        o0.y = __builtin_fmaf(-2.0f, acc[p][1], fadd_(aai, s_aaj[8 * px + 1]));
        o0.z = __builtin_fmaf(-2.0f, acc[p][2], fadd_(aai, s_aaj[8 * px + 2]));
        o0.w = __builtin_fmaf(-2.0f, acc[p][3], fadd_(aai, s_aaj[8 * px + 3]));
        o1.x = __builtin_fmaf(-2.0f, acc[p][4], fadd_(aai, s_aaj[8 * px + 4]));
        o1.y = __builtin_fmaf(-2.0f, acc[p][5], fadd_(aai, s_aaj[8 * px + 5]));
        o1.z = __builtin_fmaf(-2.0f, acc[p][6], fadd_(aai, s_aaj[8 * px + 6]));
        o1.w = __builtin_fmaf(-2.0f, acc[p][7], fadd_(aai, s_aaj[8 * px + 7]));
        float* drow = &dist[((size_t)b * NN + i) * NN + j0 + 8 * px];
        *(float4*)&drow[0] = o0;
        *(float4*)&drow[4] = o1;
    }
}

// ---------------------------------------------------------------------------
// DPP wave64 argmax combine (pure VALU, ~5 ops/step; no ds_bpermute).
// ---------------------------------------------------------------------------
template <int CTRL>
__device__ __forceinline__ void dpp_step(float& v, int& i) {
    int ovb = __builtin_amdgcn_update_dpp(0, __float_as_int(v), CTRL, 0xF, 0xF, false);
    int oi  = __builtin_amdgcn_update_dpp(0, i,                 CTRL, 0xF, 0xF, false);
    float ov = __int_as_float(ovb);
    if (ov > v || (ov == v && oi < i)) { v = ov; i = oi; }
}

// monotonic (value, lower-index-wins) packing for cross-wave u64-max keys
__device__ __forceinline__ unsigned long long pack_vi(float v, int idx) {
    unsigned u = __float_as_uint(v);
    u = ((int)u >= 0) ? (u | 0x80000000u) : ~u;
    if (v == 0.0f) u = 0x80000000u;   // normalize -0/+0 (compare equal in np)
    return ((unsigned long long)u << 32) | (unsigned)(4095 - idx);
}

// local (value, index) update, ascending-index order => first-occurrence
__device__ __forceinline__ void upd(float& bv, int& bi, float m, int idx) {
    if (m > bv) { bv = m; bi = idx; }
}

// ---------------------------------------------------------------------------
// Sequential FPS — FINAL (R0 structure, best-attested 1208us): 128 threads
// (2 waves) per batch, 32 cols/thread {512*c + 4*t + e : c=0..7}.
// R12-R23 verdict: step cost ~2800 cyc is a structural latency floor —
// one unpredictable 16KB row gather (~1000-1500 cyc mixed L3/HBM) + reduce
// (~600) + combine (~300). Probed and rejected: forced load co-residency
// (R19-R21: no effect, loads already ~1 trip), 1-wave + counted drains +
// chain-split scan (R22: -10%), 8-CU split with agent-scope exchange (R23:
// -25%, WRITE_SIZE x65 => exchange >> ingest saving). Do not re-attempt
// scheduling variants here without a new mechanism.
// ---------------------------------------------------------------------------
__global__ __launch_bounds__(128, 1) void fps_kernel(const float* __restrict__ dist,
                                                     int* __restrict__ out) {
    const int b = blockIdx.x;
    const int tid = threadIdx.x;
    const int lane = tid & 63;
    const int wave = tid >> 6;
    const float* Dm = dist + (size_t)b * NN * NN;

    __shared__ unsigned long long s_slot[2][2];
    __shared__ int s_hist[NPOINT];

    float4 m0 = make_float4(1e10f, 1e10f, 1e10f, 1e10f), m1 = m0, m2 = m0, m3 = m0;
    float4 m4 = m0, m5 = m0, m6 = m0, m7 = m0;
    int last = 0;

    for (int k = 0; k < NPOINT; ++k) {
        const float* row = Dm + (size_t)last * NN + 4 * tid;
        float4 d0 = *(const float4*)&row[0];
        float4 d1 = *(const float4*)&row[512];
        float4 d2 = *(const float4*)&row[1024];
        float4 d3 = *(const float4*)&row[1536];
        float4 d4 = *(const float4*)&row[2048];
        float4 d5 = *(const float4*)&row[2560];
        float4 d6 = *(const float4*)&row[3072];
        float4 d7 = *(const float4*)&row[3584];
        __builtin_amdgcn_sched_barrier(0);   // all 8 loads issue before any use

        if (tid == 0) s_hist[k] = last;

        m0.x = fminf(m0.x, d0.x); m0.y = fminf(m0.y, d0.y);
        m0.z = fminf(m0.z, d0.z); m0.w = fminf(m0.w, d0.w);
        m1.x = fminf(m1.x, d1.x); m1.y = fminf(m1.y, d1.y);
        m1.z = fminf(m1.z, d1.z); m1.w = fminf(m1.w, d1.w);
        m2.x = fminf(m2.x, d2.x); m2.y = fminf(m2.y, d2.y);
        m2.z = fminf(m2.z, d2.z); m2.w = fminf(m2.w, d2.w);
        m3.x = fminf(m3.x, d3.x); m3.y = fminf(m3.y, d3.y);
        m3.z = fminf(m3.z, d3.z); m3.w = fminf(m3.w, d3.w);
        m4.x = fminf(m4.x, d4.x); m4.y = fminf(m4.y, d4.y);
        m4.z = fminf(m4.z, d4.z); m4.w = fminf(m4.w, d4.w);
        m5.x = fminf(m5.x, d5.x); m5.y = fminf(m5.y, d5.y);
        m5.z = fminf(m5.z, d5.z); m5.w = fminf(m5.w, d5.w);
        m6.x = fminf(m6.x, d6.x); m6.y = fminf(m6.y, d6.y);
        m6.z = fminf(m6.z, d6.z); m6.w = fminf(m6.w, d6.w);
        m7.x = fminf(m7.x, d7.x); m7.y = fminf(m7.y, d7.y);
        m7.z = fminf(m7.z, d7.z); m7.w = fminf(m7.w, d7.w);

        // linear scan, ascending global index (first-occurrence semantics)
        const int t4 = 4 * tid;
        float bv = m0.x; int bi = t4;
        upd(bv, bi, m0.y, t4 + 1); upd(bv, bi, m0.z, t4 + 2); upd(bv, bi, m0.w, t4 + 3);
        upd(bv, bi, m1.x, 512 + t4);  upd(bv, bi, m1.y, 512 + t4 + 1);
        upd(bv, bi, m1.z, 512 + t4 + 2); upd(bv, bi, m1.w, 512 + t4 + 3);
        upd(bv, bi, m2.x, 1024 + t4); upd(bv, bi, m2.y, 1024 + t4 + 1);
        upd(bv, bi, m2.z, 1024 + t4 + 2); upd(bv, bi, m2.w, 1024 + t4 + 3);
        upd(bv, bi, m3.x, 1536 + t4); upd(bv, bi, m3.y, 1536 + t4 + 1);
        upd(bv, bi, m3.z, 1536 + t4 + 2); upd(bv, bi, m3.w, 1536 + t4 + 3);
        upd(bv, bi, m4.x, 2048 + t4); upd(bv, bi, m4.y, 2048 + t4 + 1);
        upd(bv, bi, m4.z, 2048 + t4 + 2); upd(bv, bi, m4.w, 2048 + t4 + 3);
        upd(bv, bi, m5.x, 2560 + t4); upd(bv, bi, m5.y, 2560 + t4 + 1);
        upd(bv, bi, m5.z, 2560 + t4 + 2); upd(bv, bi, m5.w, 2560 + t4 + 3);
        upd(bv, bi, m6.x, 3072 + t4); upd(bv, bi, m6.y, 3072 + t4 + 1);
        upd(bv, bi, m6.z, 3072 + t4 + 2); upd(bv, bi, m6.w, 3072 + t4 + 3);
        upd(bv, bi, m7.x, 3584 + t4); upd(bv, bi, m7.y, 3584 + t4 + 1);
        upd(bv, bi, m7.z, 3584 + t4 + 2); upd(bv, bi, m7.w, 3584 + t4 + 3);

        // wave64 DPP reduction -> lane 63, then uniform via readlane
        dpp_step<0xB1>(bv, bi);    // quad_perm [1,0,3,2]  (xor 1)
        dpp_step<0x4E>(bv, bi);    // quad_perm [2,3,0,1]  (xor 2)
        dpp_step<0x141>(bv, bi);   // row_half_mirror      (xor 4)
        dpp_step<0x140>(bv, bi);   // row_mirror           (xor 8)
        dpp_step<0x142>(bv, bi);   // row_bcast15
        dpp_step<0x143>(bv, bi);   // row_bcast31
        float wv = __int_as_float(__builtin_amdgcn_readlane(__float_as_int(bv), 63));
        int   wi = __builtin_amdgcn_readlane(bi, 63);

        // cross-wave combine (2 slots, parity dbuf, one barrier)
        const int p = k & 1;
        if (lane == 0) s_slot[p][wave] = pack_vi(wv, wi);
        __syncthreads();

        unsigned long long s0 = s_slot[p][0], s1 = s_slot[p][1];
        unsigned long long w = (s1 > s0) ? s1 : s0;
        last = 4095 - (int)(unsigned)(w & 0xFFFFFFFFull);
    }
    __syncthreads();

    // flush history: 8 ints per thread, coalesced
#pragma unroll
    for (int c = 0; c < 8; ++c)
        out[b * NPOINT + 128 * c + tid] = s_hist[128 * c + tid];
}

// ---------------------------------------------------------------------------
extern "C" void kernel_launch(void* const* d_in, const int* in_sizes, int n_in,
                              void* d_out, int out_size, void* d_ws, size_t ws_size,
                              hipStream_t stream) {
    const float* points   = (const float*)d_in[0];
    const float* features = (const float*)d_in[1];
    int* out = (int*)d_out;

    float* dist = (float*)d_ws;   // exactly 256 MiB

    dim3 g(NN / 128, NN / 128, BB);
    dist_kernel<<<g, 256, 0, stream>>>(points, features, dist);

    fps_kernel<<<BB, 128, 0, stream>>>(dist, out);
}

// Round 7
// 1525.013 us; speedup vs baseline: 1.2894x; 1.0008x over previous
//
#include <hip/hip_runtime.h>

#define BB 4
#define NN 4096
#define CC 128
#define DD 131          // 3 + 128
#define NPOINT 1024

// IEEE-exact, non-fusable fp32 ops (intrinsics are immune to -ffp-contract)
__device__ __forceinline__ float fmul_(float a, float b) { return __fmul_rn(a, b); }
__device__ __forceinline__ float fadd_(float a, float b) { return __fadd_rn(a, b); }

// ---------------------------------------------------------------------------
// dist[b][i][j] = fl(fl(aa_i + aa_j) - 2*ab_ij)   (x2 exact, one rounding)
//   ab = ascending-k single-accumulator FMA chain (Eigen gebp order)
//   aa = XLA:CPU VF8-IC4 reduce. Bit-exact semantics FROZEN per output.
// R25: 128x128 tile, 8x8/thread + SKEWED LDS. R24 post-mortem: 8-float
// fragments put the 16 b128 addresses at dword 8f, (8f)%32 in {0,8,16,24}
// => 4-way bank conflict (1.58x, m136) on every Bs read — px permutation
// cannot fix it (it only relabels which lanes collide). Skew: logical col c
// -> physical dword c + 4*(c>>5), row width 140. Fragment f starts at
// 8f + 4*(f>>2): contiguous, 16B-aligned, and starts mod 32 hit every bank
// exactly 2x => FREE (m136: 2-way = 1.02x). Traffic model: 8.6 GB LDS at
// ~52 TB/s => ~165us + staging => dist ~190-220us (was ~330).
// Arithmetic order is a pure layout remap — bit-exactness preserved.
// ---------------------------------------------------------------------------
__global__ __launch_bounds__(256) void dist_kernel(const float* __restrict__ points,
                                                   const float* __restrict__ features,
                                                   float* __restrict__ dist) {
    __shared__ float As[67][140];
    __shared__ float Bs[67][140];
    __shared__ float s_aai[128];
    __shared__ float s_aaj[128];

    const int b  = blockIdx.z;
    const int i0 = blockIdx.x * 128;
    const int j0 = blockIdx.y * 128;
    const int tid = threadIdx.x;
    const int r = tid & 127, g = tid >> 7;       // staging: 2 groups x 128
    const int tx = tid & 15;
    const int tyy = tid >> 4;                    // 16x16 thread grid
    const int rsw = r + 4 * (r >> 5);            // skewed column of r
    const int aoff = 8 * tyy + 4 * (tyy >> 2);   // skewed start of A-fragment
    const int boff = 8 * tx  + 4 * (tx  >> 2);   // skewed start of B-fragment

    // ---- stage chunk 1: k = 0..63
    for (int k = g; k < 64; k += 2) {
        float av, bv;
        if (k < 3) {
            av = points[((size_t)b * NN + i0 + r) * 3 + k];
            bv = points[((size_t)b * NN + j0 + r) * 3 + k];
        } else {
            const float* frow = features + ((size_t)b * CC + (k - 3)) * NN;
            av = frow[i0 + r];
            bv = frow[j0 + r];
        }
        As[k][rsw] = av;
        Bs[k][rsw] = bv;
    }
    __syncthreads();

    // ---- aa phases it=0,1 (k = 0..31, 32..63); 256 threads = 128 i + 128 j
    float ph[4][8];
    {
        const float (*S)[140] = (tid < 128) ? As : Bs;
#pragma unroll
        for (int j = 0; j < 4; ++j)
#pragma unroll
            for (int l = 0; l < 8; ++l) {
                float x = S[8 * j + l][rsw];
                ph[j][l] = fmul_(x, x);                       // it = 0
            }
#pragma unroll
        for (int j = 0; j < 4; ++j)
#pragma unroll
            for (int l = 0; l < 8; ++l) {
                float x = S[32 + 8 * j + l][rsw];
                ph[j][l] = fadd_(ph[j][l], fmul_(x, x));      // it = 1
            }
    }

    float acc[8][8];
#pragma unroll
    for (int p = 0; p < 8; ++p)
#pragma unroll
        for (int q = 0; q < 8; ++q) acc[p][q] = 0.f;

    // ---- FMA chunk 1: k = 0..63 (ascending, single accumulator per output)
#pragma unroll 2
    for (int kk = 0; kk < 64; ++kk) {
        float4 a0 = *(const float4*)&As[kk][aoff];
        float4 a1 = *(const float4*)&As[kk][aoff + 4];
        float4 b0 = *(const float4*)&Bs[kk][boff];
        float4 b1 = *(const float4*)&Bs[kk][boff + 4];
        const float a[8] = {a0.x, a0.y, a0.z, a0.w, a1.x, a1.y, a1.z, a1.w};
        const float c[8] = {b0.x, b0.y, b0.z, b0.w, b1.x, b1.y, b1.z, b1.w};
#pragma unroll
        for (int p = 0; p < 8; ++p)
#pragma unroll
            for (int q = 0; q < 8; ++q)
                acc[p][q] = __builtin_fmaf(a[p], c[q], acc[p][q]);
    }
    __syncthreads();

    // ---- stage chunk 2: local k = 0..66  <->  global k = 64..130
    for (int k = g; k < 67; k += 2) {
        const float* frow = features + ((size_t)b * CC + (64 + k - 3)) * NN;
        As[k][rsw] = frow[i0 + r];
        Bs[k][rsw] = frow[j0 + r];
    }
    __syncthreads();

    // ---- aa phases it=2,3 + finalize (identical tree to verified kernel)
    {
        const float (*S)[140] = (tid < 128) ? As : Bs;
#pragma unroll
        for (int j = 0; j < 4; ++j)
#pragma unroll
            for (int l = 0; l < 8; ++l) {
                float x = S[8 * j + l][rsw];
                ph[j][l] = fadd_(ph[j][l], fmul_(x, x));      // it = 2
            }
#pragma unroll
        for (int j = 0; j < 4; ++j)
#pragma unroll
            for (int l = 0; l < 8; ++l) {
                float x = S[32 + 8 * j + l][rsw];
                ph[j][l] = fadd_(ph[j][l], fmul_(x, x));      // it = 3
            }
        float v[8];
#pragma unroll
        for (int l = 0; l < 8; ++l)
            v[l] = fadd_(fadd_(fadd_(ph[0][l], ph[1][l]), ph[2][l]), ph[3][l]);
        float h4_0 = fadd_(v[0], v[4]), h4_1 = fadd_(v[1], v[5]);
        float h4_2 = fadd_(v[2], v[6]), h4_3 = fadd_(v[3], v[7]);
        float h1 = fadd_(fadd_(h4_0, h4_2), fadd_(h4_1, h4_3));
        float t0 = S[64][rsw], t1 = S[65][rsw], t2 = S[66][rsw];
        h1 = fadd_(h1, fmul_(t0, t0));
        h1 = fadd_(h1, fmul_(t1, t1));
        h1 = fadd_(h1, fmul_(t2, t2));
        if (tid < 128) s_aai[r] = h1; else s_aaj[r] = h1;
    }

    // ---- FMA chunk 2: global k = 64..130
#pragma unroll 2
    for (int kk = 0; kk < 67; ++kk) {
        float4 a0 = *(const float4*)&As[kk][aoff];
        float4 a1 = *(const float4*)&As[kk][aoff + 4];
        float4 b0 = *(const float4*)&Bs[kk][boff];
        float4 b1 = *(const float4*)&Bs[kk][boff + 4];
        const float a[8] = {a0.x, a0.y, a0.z, a0.w, a1.x, a1.y, a1.z, a1.w};
        const float c[8] = {b0.x, b0.y, b0.z, b0.w, b1.x, b1.y, b1.z, b1.w};
#pragma unroll
        for (int p = 0; p < 8; ++p)
#pragma unroll
            for (int q = 0; q < 8; ++q)
                acc[p][q] = __builtin_fmaf(a[p], c[q], acc[p][q]);
    }
    __syncthreads();

    // ---- epilogue: x2-exact combine, one rounding; plain ordered cols
#pragma unroll
    for (int p = 0; p < 8; ++p) {
        const int i = i0 + 8 * tyy + p;
        const float aai = s_aai[8 * tyy + p];
        float4 o0, o1;
        o0.x = __builtin_fmaf(-2.0f, acc[p][0], fadd_(aai, s_aaj[8 * tx + 0]));
        o0.y = __builtin_fmaf(-2.0f, acc[p][1], fadd_(aai, s_aaj[8 * tx + 1]));
        o0.z = __builtin_fmaf(-2.0f, acc[p][2], fadd_(aai, s_aaj[8 * tx + 2]));
        o0.w = __builtin_fmaf(-2.0f, acc[p][3], fadd_(aai, s_aaj[8 * tx + 3]));
        o1.x = __builtin_fmaf(-2.0f, acc[p][4], fadd_(aai, s_aaj[8 * tx + 4]));
        o1.y = __builtin_fmaf(-2.0f, acc[p][5], fadd_(aai, s_aaj[8 * tx + 5]));
        o1.z = __builtin_fmaf(-2.0f, acc[p][6], fadd_(aai, s_aaj[8 * tx + 6]));
        o1.w = __builtin_fmaf(-2.0f, acc[p][7], fadd_(aai, s_aaj[8 * tx + 7]));
        float* drow = &dist[((size_t)b * NN + i) * NN + j0 + 8 * tx];
        *(float4*)&drow[0] = o0;
        *(float4*)&drow[4] = o1;
    }
}

// ---------------------------------------------------------------------------
// DPP wave64 argmax combine (pure VALU, ~5 ops/step; no ds_bpermute).
// ---------------------------------------------------------------------------
template <int CTRL>
__device__ __forceinline__ void dpp_step(float& v, int& i) {
    int ovb = __builtin_amdgcn_update_dpp(0, __float_as_int(v), CTRL, 0xF, 0xF, false);
    int oi  = __builtin_amdgcn_update_dpp(0, i,                 CTRL, 0xF, 0xF, false);
    float ov = __int_as_float(ovb);
    if (ov > v || (ov == v && oi < i)) { v = ov; i = oi; }
}

// monotonic (value, lower-index-wins) packing for cross-wave u64-max keys
__device__ __forceinline__ unsigned long long pack_vi(float v, int idx) {
    unsigned u = __float_as_uint(v);
    u = ((int)u >= 0) ? (u | 0x80000000u) : ~u;
    if (v == 0.0f) u = 0x80000000u;   // normalize -0/+0 (compare equal in np)
    return ((unsigned long long)u << 32) | (unsigned)(4095 - idx);
}

// local (value, index) update, ascending-index order => first-occurrence
__device__ __forceinline__ void upd(float& bv, int& bi, float m, int idx) {
    if (m > bv) { bv = m; bi = idx; }
}

// ---------------------------------------------------------------------------
// Sequential FPS — FINAL (R0 structure, attested 1196-1208us): 128 threads
// (2 waves) per batch, 32 cols/thread {512*c + 4*t + e : c=0..7}.
// R12-R23 verdict: step cost ~2800 cyc is a structural latency floor —
// one unpredictable 16KB row gather (~1000-1500 cyc mixed L3/HBM) + reduce
// (~600) + combine (~300). Probed and rejected: forced load co-residency
// (R19-R21: no effect, loads already ~1 trip), 1-wave + counted drains +
// chain-split scan (R22: -10%), 8-CU split with agent-scope exchange (R23:
// -25%, WRITE_SIZE x65 => exchange >> ingest saving). Do not re-attempt
// scheduling variants here without a new mechanism.
// ---------------------------------------------------------------------------
__global__ __launch_bounds__(128, 1) void fps_kernel(const float* __restrict__ dist,
                                                     int* __restrict__ out) {
    const int b = blockIdx.x;
    const int tid = threadIdx.x;
    const int lane = tid & 63;
    const int wave = tid >> 6;
    const float* Dm = dist + (size_t)b * NN * NN;

    __shared__ unsigned long long s_slot[2][2];
    __shared__ int s_hist[NPOINT];

    float4 m0 = make_float4(1e10f, 1e10f, 1e10f, 1e10f), m1 = m0, m2 = m0, m3 = m0;
    float4 m4 = m0, m5 = m0, m6 = m0, m7 = m0;
    int last = 0;

    for (int k = 0; k < NPOINT; ++k) {
        const float* row = Dm + (size_t)last * NN + 4 * tid;
        float4 d0 = *(const float4*)&row[0];
        float4 d1 = *(const float4*)&row[512];
        float4 d2 = *(const float4*)&row[1024];
        float4 d3 = *(const float4*)&row[1536];
        float4 d4 = *(const float4*)&row[2048];
        float4 d5 = *(const float4*)&row[2560];
        float4 d6 = *(const float4*)&row[3072];
        float4 d7 = *(const float4*)&row[3584];
        __builtin_amdgcn_sched_barrier(0);   // all 8 loads issue before any use

        if (tid == 0) s_hist[k] = last;

        m0.x = fminf(m0.x, d0.x); m0.y = fminf(m0.y, d0.y);
        m0.z = fminf(m0.z, d0.z); m0.w = fminf(m0.w, d0.w);
        m1.x = fminf(m1.x, d1.x); m1.y = fminf(m1.y, d1.y);
        m1.z = fminf(m1.z, d1.z); m1.w = fminf(m1.w, d1.w);
        m2.x = fminf(m2.x, d2.x); m2.y = fminf(m2.y, d2.y);
        m2.z = fminf(m2.z, d2.z); m2.w = fminf(m2.w, d2.w);
        m3.x = fminf(m3.x, d3.x); m3.y = fminf(m3.y, d3.y);
        m3.z = fminf(m3.z, d3.z); m3.w = fminf(m3.w, d3.w);
        m4.x = fminf(m4.x, d4.x); m4.y = fminf(m4.y, d4.y);
        m4.z = fminf(m4.z, d4.z); m4.w = fminf(m4.w, d4.w);
        m5.x = fminf(m5.x, d5.x); m5.y = fminf(m5.y, d5.y);
        m5.z = fminf(m5.z, d5.z); m5.w = fminf(m5.w, d5.w);
        m6.x = fminf(m6.x, d6.x); m6.y = fminf(m6.y, d6.y);
        m6.z = fminf(m6.z, d6.z); m6.w = fminf(m6.w, d6.w);
        m7.x = fminf(m7.x, d7.x); m7.y = fminf(m7.y, d7.y);
        m7.z = fminf(m7.z, d7.z); m7.w = fminf(m7.w, d7.w);

        // linear scan, ascending global index (first-occurrence semantics)
        const int t4 = 4 * tid;
        float bv = m0.x; int bi = t4;
        upd(bv, bi, m0.y, t4 + 1); upd(bv, bi, m0.z, t4 + 2); upd(bv, bi, m0.w, t4 + 3);
        upd(bv, bi, m1.x, 512 + t4);  upd(bv, bi, m1.y, 512 + t4 + 1);
        upd(bv, bi, m1.z, 512 + t4 + 2); upd(bv, bi, m1.w, 512 + t4 + 3);
        upd(bv, bi, m2.x, 1024 + t4); upd(bv, bi, m2.y, 1024 + t4 + 1);
        upd(bv, bi, m2.z, 1024 + t4 + 2); upd(bv, bi, m2.w, 1024 + t4 + 3);
        upd(bv, bi, m3.x, 1536 + t4); upd(bv, bi, m3.y, 1536 + t4 + 1);
        upd(bv, bi, m3.z, 1536 + t4 + 2); upd(bv, bi, m3.w, 1536 + t4 + 3);
        upd(bv, bi, m4.x, 2048 + t4); upd(bv, bi, m4.y, 2048 + t4 + 1);
        upd(bv, bi, m4.z, 2048 + t4 + 2); upd(bv, bi, m4.w, 2048 + t4 + 3);
        upd(bv, bi, m5.x, 2560 + t4); upd(bv, bi, m5.y, 2560 + t4 + 1);
        upd(bv, bi, m5.z, 2560 + t4 + 2); upd(bv, bi, m5.w, 2560 + t4 + 3);
        upd(bv, bi, m6.x, 3072 + t4); upd(bv, bi, m6.y, 3072 + t4 + 1);
        upd(bv, bi, m6.z, 3072 + t4 + 2); upd(bv, bi, m6.w, 3072 + t4 + 3);
        upd(bv, bi, m7.x, 3584 + t4); upd(bv, bi, m7.y, 3584 + t4 + 1);
        upd(bv, bi, m7.z, 3584 + t4 + 2); upd(bv, bi, m7.w, 3584 + t4 + 3);

        // wave64 DPP reduction -> lane 63, then uniform via readlane
        dpp_step<0xB1>(bv, bi);    // quad_perm [1,0,3,2]  (xor 1)
        dpp_step<0x4E>(bv, bi);    // quad_perm [2,3,0,1]  (xor 2)
        dpp_step<0x141>(bv, bi);   // row_half_mirror      (xor 4)
        dpp_step<0x140>(bv, bi);   // row_mirror           (xor 8)
        dpp_step<0x142>(bv, bi);   // row_bcast15
        dpp_step<0x143>(bv, bi);   // row_bcast31
        float wv = __int_as_float(__builtin_amdgcn_readlane(__float_as_int(bv), 63));
        int   wi = __builtin_amdgcn_readlane(bi, 63);

        // cross-wave combine (2 slots, parity dbuf, one barrier)
        const int p = k & 1;
        if (lane == 0) s_slot[p][wave] = pack_vi(wv, wi);
        __syncthreads();

        unsigned long long s0 = s_slot[p][0], s1 = s_slot[p][1];
        unsigned long long w = (s1 > s0) ? s1 : s0;
        last = 4095 - (int)(unsigned)(w & 0xFFFFFFFFull);
    }
    __syncthreads();

    // flush history: 8 ints per thread, coalesced
#pragma unroll
    for (int c = 0; c < 8; ++c)
        out[b * NPOINT + 128 * c + tid] = s_hist[128 * c + tid];
}

// ---------------------------------------------------------------------------
extern "C" void kernel_launch(void* const* d_in, const int* in_sizes, int n_in,
                              void* d_out, int out_size, void* d_ws, size_t ws_size,
                              hipStream_t stream) {
    const float* points   = (const float*)d_in[0];
    const float* features = (const float*)d_in[1];
    int* out = (int*)d_out;

    float* dist = (float*)d_ws;   // exactly 256 MiB

    dim3 g(NN / 128, NN / 128, BB);
    dist_kernel<<<g, 256, 0, stream>>>(points, features, dist);

    fps_kernel<<<BB, 128, 0, stream>>>(dist, out);
}

// Round 8
// 1501.933 us; speedup vs baseline: 1.3093x; 1.0154x over previous
//
#include <hip/hip_runtime.h>

#define BB 4
#define NN 4096
#define CC 128
#define DD 131          // 3 + 128
#define NPOINT 1024

// IEEE-exact, non-fusable fp32 ops (intrinsics are immune to -ffp-contract)
__device__ __forceinline__ float fmul_(float a, float b) { return __fmul_rn(a, b); }
__device__ __forceinline__ float fadd_(float a, float b) { return __fadd_rn(a, b); }

// ---------------------------------------------------------------------------
// dist[b][i][j] = fl(fl(aa_i + aa_j) - 2*ab_ij)   (x2 exact, one rounding)
//   ab = ascending-k single-accumulator FMA chain (Eigen gebp order)
//   aa = XLA:CPU VF8-IC4 reduce. VERIFIED bit-exact (absmax 0 across rounds).
// FINAL: 64x64 tile, 4x4/thread, k-major LDS, two K chunks — the attested
// fastest dist (~304us). Probed and rejected: 128x128/8x8 (R24, 4-way bank
// conflict on 8-float fragments, net wash) and 128x128+skewed LDS (R25,
// conflict-free but occupancy/phase losses eat the traffic halving — both
// land at ~325us). dist sits ~2.7x over the 112us FMA-issue floor under all
// three tilings; the binding resource is NOT LDS banking. Frozen.
// ---------------------------------------------------------------------------
__global__ __launch_bounds__(256) void dist_kernel(const float* __restrict__ points,
                                                   const float* __restrict__ features,
                                                   float* __restrict__ dist) {
    __shared__ float As[67][64];
    __shared__ float Bs[67][64];
    __shared__ float s_aai[64];
    __shared__ float s_aaj[64];

    const int b  = blockIdx.z;
    const int i0 = blockIdx.x * 64;
    const int j0 = blockIdx.y * 64;
    const int tid = threadIdx.x;
    const int r = tid & 63, g = tid >> 6;
    const int tx = tid & 15;
    const int ty = tid >> 4;

    for (int k = g; k < 64; k += 4) {
        float av, bv;
        if (k < 3) {
            av = points[((size_t)b * NN + i0 + r) * 3 + k];
            bv = points[((size_t)b * NN + j0 + r) * 3 + k];
        } else {
            const float* frow = features + ((size_t)b * CC + (k - 3)) * NN;
            av = frow[i0 + r];
            bv = frow[j0 + r];
        }
        As[k][r] = av;
        Bs[k][r] = bv;
    }
    __syncthreads();

    float ph[4][8];
    if (tid < 128) {
        const int rr = tid & 63;
        const float (*S)[64] = (tid < 64) ? As : Bs;
#pragma unroll
        for (int j = 0; j < 4; ++j)
#pragma unroll
            for (int l = 0; l < 8; ++l) {
                float x = S[8 * j + l][rr];
                ph[j][l] = fmul_(x, x);                       // it = 0
            }
#pragma unroll
        for (int j = 0; j < 4; ++j)
#pragma unroll
            for (int l = 0; l < 8; ++l) {
                float x = S[32 + 8 * j + l][rr];
                ph[j][l] = fadd_(ph[j][l], fmul_(x, x));      // it = 1
            }
    }

    float acc[4][4];
#pragma unroll
    for (int p = 0; p < 4; ++p)
#pragma unroll
        for (int q = 0; q < 4; ++q) acc[p][q] = 0.f;

#pragma unroll 4
    for (int kk = 0; kk < 64; ++kk) {
        float4 a4 = *(const float4*)&As[kk][4 * ty];
        float4 b4 = *(const float4*)&Bs[kk][4 * tx];
        const float a[4] = {a4.x, a4.y, a4.z, a4.w};
        const float c[4] = {b4.x, b4.y, b4.z, b4.w};
#pragma unroll
        for (int p = 0; p < 4; ++p)
#pragma unroll
            for (int q = 0; q < 4; ++q)
                acc[p][q] = __builtin_fmaf(a[p], c[q], acc[p][q]);
    }
    __syncthreads();

    for (int k = g; k < 67; k += 4) {
        const float* frow = features + ((size_t)b * CC + (64 + k - 3)) * NN;
        As[k][r] = frow[i0 + r];
        Bs[k][r] = frow[j0 + r];
    }
    __syncthreads();

    if (tid < 128) {
        const int rr = tid & 63;
        const float (*S)[64] = (tid < 64) ? As : Bs;
#pragma unroll
        for (int j = 0; j < 4; ++j)
#pragma unroll
            for (int l = 0; l < 8; ++l) {
                float x = S[8 * j + l][rr];
                ph[j][l] = fadd_(ph[j][l], fmul_(x, x));      // it = 2
            }
#pragma unroll
        for (int j = 0; j < 4; ++j)
#pragma unroll
            for (int l = 0; l < 8; ++l) {
                float x = S[32 + 8 * j + l][rr];
                ph[j][l] = fadd_(ph[j][l], fmul_(x, x));      // it = 3
            }
        float v[8];
#pragma unroll
        for (int l = 0; l < 8; ++l)
            v[l] = fadd_(fadd_(fadd_(ph[0][l], ph[1][l]), ph[2][l]), ph[3][l]);
        float h4_0 = fadd_(v[0], v[4]), h4_1 = fadd_(v[1], v[5]);
        float h4_2 = fadd_(v[2], v[6]), h4_3 = fadd_(v[3], v[7]);
        float h1 = fadd_(fadd_(h4_0, h4_2), fadd_(h4_1, h4_3));
        float t0 = S[64][rr], t1 = S[65][rr], t2 = S[66][rr];
        h1 = fadd_(h1, fmul_(t0, t0));
        h1 = fadd_(h1, fmul_(t1, t1));
        h1 = fadd_(h1, fmul_(t2, t2));
        if (tid < 64) s_aai[rr] = h1; else s_aaj[rr] = h1;
    }

#pragma unroll 4
    for (int kk = 0; kk < 67; ++kk) {
        float4 a4 = *(const float4*)&As[kk][4 * ty];
        float4 b4 = *(const float4*)&Bs[kk][4 * tx];
        const float a[4] = {a4.x, a4.y, a4.z, a4.w};
        const float c[4] = {b4.x, b4.y, b4.z, b4.w};
#pragma unroll
        for (int p = 0; p < 4; ++p)
#pragma unroll
            for (int q = 0; q < 4; ++q)
                acc[p][q] = __builtin_fmaf(a[p], c[q], acc[p][q]);
    }
    __syncthreads();

#pragma unroll
    for (int p = 0; p < 4; ++p) {
        const int i = i0 + 4 * ty + p;
        const float aai = s_aai[4 * ty + p];
        float4 o;
        o.x = __builtin_fmaf(-2.0f, acc[p][0], fadd_(aai, s_aaj[4 * tx + 0]));
        o.y = __builtin_fmaf(-2.0f, acc[p][1], fadd_(aai, s_aaj[4 * tx + 1]));
        o.z = __builtin_fmaf(-2.0f, acc[p][2], fadd_(aai, s_aaj[4 * tx + 2]));
        o.w = __builtin_fmaf(-2.0f, acc[p][3], fadd_(aai, s_aaj[4 * tx + 3]));
        *(float4*)&dist[((size_t)b * NN + i) * NN + j0 + 4 * tx] = o;
    }
}

// ---------------------------------------------------------------------------
// DPP wave64 argmax combine (pure VALU, ~5 ops/step; no ds_bpermute).
// ---------------------------------------------------------------------------
template <int CTRL>
__device__ __forceinline__ void dpp_step(float& v, int& i) {
    int ovb = __builtin_amdgcn_update_dpp(0, __float_as_int(v), CTRL, 0xF, 0xF, false);
    int oi  = __builtin_amdgcn_update_dpp(0, i,                 CTRL, 0xF, 0xF, false);
    float ov = __int_as_float(ovb);
    if (ov > v || (ov == v && oi < i)) { v = ov; i = oi; }
}

// monotonic (value, lower-index-wins) packing for cross-wave u64-max keys
__device__ __forceinline__ unsigned long long pack_vi(float v, int idx) {
    unsigned u = __float_as_uint(v);
    u = ((int)u >= 0) ? (u | 0x80000000u) : ~u;
    if (v == 0.0f) u = 0x80000000u;   // normalize -0/+0 (compare equal in np)
    return ((unsigned long long)u << 32) | (unsigned)(4095 - idx);
}

// local (value, index) update, ascending-index order => first-occurrence
__device__ __forceinline__ void upd(float& bv, int& bi, float m, int idx) {
    if (m > bv) { bv = m; bi = idx; }
}

// ---------------------------------------------------------------------------
// Sequential FPS — FINAL (R0 structure, attested 1196-1208us): 128 threads
// (2 waves) per batch, 32 cols/thread {512*c + 4*t + e : c=0..7}.
// R12-R23 verdict: step cost ~2800 cyc is a structural latency floor —
// one unpredictable 16KB row gather (~1000-1500 cyc mixed L3/HBM) + reduce
// (~600) + combine (~300). Probed and rejected: forced load co-residency
// (R19-R21: no effect, loads already ~1 trip), 1-wave + counted drains +
// chain-split scan (R22: -10%), 8-CU split with agent-scope exchange (R23:
// -25%, WRITE_SIZE x65 => exchange >> ingest saving). Do not re-attempt
// scheduling variants here without a new mechanism.
// ---------------------------------------------------------------------------
__global__ __launch_bounds__(128, 1) void fps_kernel(const float* __restrict__ dist,
                                                     int* __restrict__ out) {
    const int b = blockIdx.x;
    const int tid = threadIdx.x;
    const int lane = tid & 63;
    const int wave = tid >> 6;
    const float* Dm = dist + (size_t)b * NN * NN;

    __shared__ unsigned long long s_slot[2][2];
    __shared__ int s_hist[NPOINT];

    float4 m0 = make_float4(1e10f, 1e10f, 1e10f, 1e10f), m1 = m0, m2 = m0, m3 = m0;
    float4 m4 = m0, m5 = m0, m6 = m0, m7 = m0;
    int last = 0;

    for (int k = 0; k < NPOINT; ++k) {
        const float* row = Dm + (size_t)last * NN + 4 * tid;
        float4 d0 = *(const float4*)&row[0];
        float4 d1 = *(const float4*)&row[512];
        float4 d2 = *(const float4*)&row[1024];
        float4 d3 = *(const float4*)&row[1536];
        float4 d4 = *(const float4*)&row[2048];
        float4 d5 = *(const float4*)&row[2560];
        float4 d6 = *(const float4*)&row[3072];
        float4 d7 = *(const float4*)&row[3584];
        __builtin_amdgcn_sched_barrier(0);   // all 8 loads issue before any use

        if (tid == 0) s_hist[k] = last;

        m0.x = fminf(m0.x, d0.x); m0.y = fminf(m0.y, d0.y);
        m0.z = fminf(m0.z, d0.z); m0.w = fminf(m0.w, d0.w);
        m1.x = fminf(m1.x, d1.x); m1.y = fminf(m1.y, d1.y);
        m1.z = fminf(m1.z, d1.z); m1.w = fminf(m1.w, d1.w);
        m2.x = fminf(m2.x, d2.x); m2.y = fminf(m2.y, d2.y);
        m2.z = fminf(m2.z, d2.z); m2.w = fminf(m2.w, d2.w);
        m3.x = fminf(m3.x, d3.x); m3.y = fminf(m3.y, d3.y);
        m3.z = fminf(m3.z, d3.z); m3.w = fminf(m3.w, d3.w);
        m4.x = fminf(m4.x, d4.x); m4.y = fminf(m4.y, d4.y);
        m4.z = fminf(m4.z, d4.z); m4.w = fminf(m4.w, d4.w);
        m5.x = fminf(m5.x, d5.x); m5.y = fminf(m5.y, d5.y);
        m5.z = fminf(m5.z, d5.z); m5.w = fminf(m5.w, d5.w);
        m6.x = fminf(m6.x, d6.x); m6.y = fminf(m6.y, d6.y);
        m6.z = fminf(m6.z, d6.z); m6.w = fminf(m6.w, d6.w);
        m7.x = fminf(m7.x, d7.x); m7.y = fminf(m7.y, d7.y);
        m7.z = fminf(m7.z, d7.z); m7.w = fminf(m7.w, d7.w);

        // linear scan, ascending global index (first-occurrence semantics)
        const int t4 = 4 * tid;
        float bv = m0.x; int bi = t4;
        upd(bv, bi, m0.y, t4 + 1); upd(bv, bi, m0.z, t4 + 2); upd(bv, bi, m0.w, t4 + 3);
        upd(bv, bi, m1.x, 512 + t4);  upd(bv, bi, m1.y, 512 + t4 + 1);
        upd(bv, bi, m1.z, 512 + t4 + 2); upd(bv, bi, m1.w, 512 + t4 + 3);
        upd(bv, bi, m2.x, 1024 + t4); upd(bv, bi, m2.y, 1024 + t4 + 1);
        upd(bv, bi, m2.z, 1024 + t4 + 2); upd(bv, bi, m2.w, 1024 + t4 + 3);
        upd(bv, bi, m3.x, 1536 + t4); upd(bv, bi, m3.y, 1536 + t4 + 1);
        upd(bv, bi, m3.z, 1536 + t4 + 2); upd(bv, bi, m3.w, 1536 + t4 + 3);
        upd(bv, bi, m4.x, 2048 + t4); upd(bv, bi, m4.y, 2048 + t4 + 1);
        upd(bv, bi, m4.z, 2048 + t4 + 2); upd(bv, bi, m4.w, 2048 + t4 + 3);
        upd(bv, bi, m5.x, 2560 + t4); upd(bv, bi, m5.y, 2560 + t4 + 1);
        upd(bv, bi, m5.z, 2560 + t4 + 2); upd(bv, bi, m5.w, 2560 + t4 + 3);
        upd(bv, bi, m6.x, 3072 + t4); upd(bv, bi, m6.y, 3072 + t4 + 1);
        upd(bv, bi, m6.z, 3072 + t4 + 2); upd(bv, bi, m6.w, 3072 + t4 + 3);
        upd(bv, bi, m7.x, 3584 + t4); upd(bv, bi, m7.y, 3584 + t4 + 1);
        upd(bv, bi, m7.z, 3584 + t4 + 2); upd(bv, bi, m7.w, 3584 + t4 + 3);

        // wave64 DPP reduction -> lane 63, then uniform via readlane
        dpp_step<0xB1>(bv, bi);    // quad_perm [1,0,3,2]  (xor 1)
        dpp_step<0x4E>(bv, bi);    // quad_perm [2,3,0,1]  (xor 2)
        dpp_step<0x141>(bv, bi);   // row_half_mirror      (xor 4)
        dpp_step<0x140>(bv, bi);   // row_mirror           (xor 8)
        dpp_step<0x142>(bv, bi);   // row_bcast15
        dpp_step<0x143>(bv, bi);   // row_bcast31
        float wv = __int_as_float(__builtin_amdgcn_readlane(__float_as_int(bv), 63));
        int   wi = __builtin_amdgcn_readlane(bi, 63);

        // cross-wave combine (2 slots, parity dbuf, one barrier)
        const int p = k & 1;
        if (lane == 0) s_slot[p][wave] = pack_vi(wv, wi);
        __syncthreads();

        unsigned long long s0 = s_slot[p][0], s1 = s_slot[p][1];
        unsigned long long w = (s1 > s0) ? s1 : s0;
        last = 4095 - (int)(unsigned)(w & 0xFFFFFFFFull);
    }
    __syncthreads();

    // flush history: 8 ints per thread, coalesced
#pragma unroll
    for (int c = 0; c < 8; ++c)
        out[b * NPOINT + 128 * c + tid] = s_hist[128 * c + tid];
}

// ---------------------------------------------------------------------------
extern "C" void kernel_launch(void* const* d_in, const int* in_sizes, int n_in,
                              void* d_out, int out_size, void* d_ws, size_t ws_size,
                              hipStream_t stream) {
    const float* points   = (const float*)d_in[0];
    const float* features = (const float*)d_in[1];
    int* out = (int*)d_out;

    float* dist = (float*)d_ws;   // exactly 256 MiB

    dim3 g(NN / 64, NN / 64, BB);
    dist_kernel<<<g, 256, 0, stream>>>(points, features, dist);

    fps_kernel<<<BB, 128, 0, stream>>>(dist, out);
}